// Round 8
// baseline (129.240 us; speedup 1.0000x reference)
//
#include <hip/hip_runtime.h>
#include <math.h>

// DTM weighted-quantile kernel.
// One wave64 per (b, n) output. M=2048 points -> 32 per lane in registers.
// Binary search over float bit-patterns finds the exact k-th smallest d2
// (the value a full sort would select), then strict-below partial sums give
// the reference's  val = cumD[k] + d2[k]*(bound - wcum[k])  tie-independently.
// Output dtype: float32 (reference output dtype). Harness compares at bf16
// tolerance.
//
// BUGFIX (round 6): midpoint was (lo+hi)>>1 with hi=0x7F800000 -> signed int
// overflow (UB) whenever lo >= 0x00800000, i.e. for every grid point whose
// first probe (midf~1.5) undershoots the mass bound (corner points). Clang
// exploited the UB and the loop degenerated to r2=+inf there -> NaN (round 1)
// / zeros (rounds 2,5) at exactly the max-DTM corners (absmax 0.953125).
// Overflow-free form: mid = lo + ((hi-lo)>>1); hi-lo <= 0x7F800001 always fits.

#define M_POINTS 2048
#define PER_LANE 32  // M_POINTS / 64
#define M0 0.3f

__device__ __forceinline__ float wave_reduce_sum(float v) {
    #pragma unroll
    for (int off = 1; off < 64; off <<= 1)
        v += __shfl_xor(v, off, 64);
    return v;
}

__global__ __launch_bounds__(256) void dtm_kernel(
    const float* __restrict__ inputs,   // [B, M, 2]
    const float* __restrict__ weight,   // [B, M]
    const float* __restrict__ grid,     // [N, 2]
    float* __restrict__ out,            // [B, N]  (f32)
    int B, int N)
{
    const int lane = threadIdx.x & 63;
    const int gwave = blockIdx.x * (blockDim.x >> 6) + (threadIdx.x >> 6);
    if (gwave >= B * N) return;           // wave-uniform exit
    const int b = gwave / N;
    const int n = gwave - b * N;

    const float gx = grid[2 * n];
    const float gy = grid[2 * n + 1];

    const float* __restrict__ inb = inputs + (size_t)b * M_POINTS * 2;
    const float* __restrict__ wb  = weight + (size_t)b * M_POINTS;

    float d2[PER_LANE], w[PER_LANE];
    float wsum_local = 0.0f;
    #pragma unroll
    for (int j = 0; j < PER_LANE; ++j) {
        const int m = lane + 64 * j;                       // coalesced
        const float2 xy = *reinterpret_cast<const float2*>(inb + 2 * m);
        const float wt = wb[m];
        const float dx = xy.x - gx;
        const float dy = xy.y - gy;
        d2[j] = fmaf(dx, dx, dy * dy);
        w[j]  = wt;
        wsum_local += wt;
    }
    const float bound = M0 * wave_reduce_sum(wsum_local);  // == wB

    // Binary search on float bit patterns (monotonic for d2 >= 0) for the
    // smallest r2 such that  sum(w_i | d2_i <= r2) >= bound.
    // Invariant: cnt(float(lo)) < bound <= cnt(float(hi)).
    int lo = -1;                 // conceptually "below every value"
    int hi = 0x7F800000;         // +inf: cnt = full weight sum >= bound
    #pragma unroll 1
    for (int it = 0; it < 31; ++it) {
        const int mid = lo + ((hi - lo) >> 1);   // overflow-free midpoint
        const float midf = __int_as_float(mid);
        float c = 0.0f;
        #pragma unroll
        for (int j = 0; j < PER_LANE; ++j)
            c += (d2[j] <= midf) ? w[j] : 0.0f;
        c = wave_reduce_sum(c);
        if (c >= bound) hi = mid; else lo = mid; // uniform across wave
    }
    const float r2 = __int_as_float(hi);         // exact k-th smallest d2

    // Strict-below partial sums (tie-order independent form of the reference).
    float S = 0.0f, W = 0.0f;
    #pragma unroll
    for (int j = 0; j < PER_LANE; ++j) {
        if (d2[j] < r2) {
            S = fmaf(w[j], d2[j], S);
            W += w[j];
        }
    }
    S = wave_reduce_sum(S);
    W = wave_reduce_sum(W);

    // True math guarantees W_strict < bound; clamps remove FP-noise sign flips.
    const float margin = fmaxf(bound - W, 0.0f);
    const float val = fmaxf(fmaf(r2, margin, S), 0.0f);
    if (lane == 0) out[gwave] = sqrtf(val / bound);
}

extern "C" void kernel_launch(void* const* d_in, const int* in_sizes, int n_in,
                              void* d_out, int out_size, void* d_ws, size_t ws_size,
                              hipStream_t stream) {
    const float* inputs = (const float*)d_in[0];   // [B, M, 2]
    const float* weight = (const float*)d_in[1];   // [B, M]
    const float* grid   = (const float*)d_in[2];   // [N, 2]
    float* out = (float*)d_out;                    // [B, N] f32

    const int N = in_sizes[2] / 2;                 // 6561
    const int B = out_size / N;                    // 2
    // M is hard-wired to 2048 (PER_LANE*64) per the problem spec.

    const int total_waves = B * N;                 // 13122
    const int waves_per_block = 256 / 64;
    const int blocks = (total_waves + waves_per_block - 1) / waves_per_block;

    dtm_kernel<<<blocks, 256, 0, stream>>>(inputs, weight, grid, out, B, N);
}

// Round 10
// 128.240 us; speedup vs baseline: 1.0078x; 1.0078x over previous
//
#include <hip/hip_runtime.h>
#include <math.h>

// DTM weighted-quantile kernel, v2: value-space bisection + exact extraction.
// One wave64 per (b, n) output. M=2048 points -> 32 contiguous per lane in
// registers (float4-vectorized staging).
//
// r2 = min{ v in {d2_i} : sum_{d2_i <= v} w_i >= bound },  bound = 0.3*sum(w).
// Phase 1: bisect on VALUES (vmid = (vlo+vhi)/2), tracking bracket weights;
//          early-exit when interval weight <= 0.75 (~<=2 elements) instead of
//          grinding 31 bit-space iterations (measured 97% VALUBusy at r8 =>
//          issue-bound; this cuts ~60% of the count-pass work).
// Phase 2: exact extraction - enumerate distinct values in (vlo,vhi] ascending
//          until cnt >= bound. Handles ties/stuck-midpoint exactly; also
//          yields W_strict = wlo for free.
// Phase 3: S = sum_{d2 < r2} w*d2 pass; val = S + r2*(bound - W); sqrt.

#define M_POINTS 2048
#define PER_LANE 32  // M_POINTS / 64
#define M0 0.3f

__device__ __forceinline__ float wave_reduce_sum(float v) {
    #pragma unroll
    for (int off = 1; off < 64; off <<= 1)
        v += __shfl_xor(v, off, 64);
    return v;
}
__device__ __forceinline__ float wave_reduce_max(float v) {
    #pragma unroll
    for (int off = 1; off < 64; off <<= 1)
        v = fmaxf(v, __shfl_xor(v, off, 64));
    return v;
}
__device__ __forceinline__ float wave_reduce_min(float v) {
    #pragma unroll
    for (int off = 1; off < 64; off <<= 1)
        v = fminf(v, __shfl_xor(v, off, 64));
    return v;
}

__global__ __launch_bounds__(256) void dtm_kernel(
    const float* __restrict__ inputs,   // [B, M, 2]
    const float* __restrict__ weight,   // [B, M]
    const float* __restrict__ grid,     // [N, 2]
    float* __restrict__ out,            // [B, N]  (f32)
    int B, int N)
{
    const int lane = threadIdx.x & 63;
    const int gwave = blockIdx.x * (blockDim.x >> 6) + (threadIdx.x >> 6);
    if (gwave >= B * N) return;           // wave-uniform exit
    const int b = gwave / N;
    const int n = gwave - b * N;

    const float gx = grid[2 * n];
    const float gy = grid[2 * n + 1];

    const float* __restrict__ inb = inputs + (size_t)b * M_POINTS * 2;
    const float* __restrict__ wb  = weight + (size_t)b * M_POINTS;

    // Contiguous 32 elements per lane -> float4 staging (24 VMEM inst vs 96).
    const int base = lane * PER_LANE;
    const float4* __restrict__ xyv = reinterpret_cast<const float4*>(inb + 2 * base);
    const float4* __restrict__ wv  = reinterpret_cast<const float4*>(wb + base);

    float d2[PER_LANE], w[PER_LANE];
    float wsum_local = 0.0f, vmax_local = 0.0f;
    #pragma unroll
    for (int q = 0; q < PER_LANE / 4; ++q) {
        const float4 wq = wv[q];
        const float4 a  = xyv[2 * q];       // x0 y0 x1 y1
        const float4 c4 = xyv[2 * q + 1];   // x2 y2 x3 y3
        float dx, dy;
        dx = a.x  - gx; dy = a.y  - gy; d2[4*q+0] = fmaf(dx, dx, dy * dy);
        dx = a.z  - gx; dy = a.w  - gy; d2[4*q+1] = fmaf(dx, dx, dy * dy);
        dx = c4.x - gx; dy = c4.y - gy; d2[4*q+2] = fmaf(dx, dx, dy * dy);
        dx = c4.z - gx; dy = c4.w - gy; d2[4*q+3] = fmaf(dx, dx, dy * dy);
        w[4*q+0] = wq.x; w[4*q+1] = wq.y; w[4*q+2] = wq.z; w[4*q+3] = wq.w;
        wsum_local += wq.x + wq.y + wq.z + wq.w;
        vmax_local = fmaxf(vmax_local, fmaxf(fmaxf(d2[4*q+0], d2[4*q+1]),
                                             fmaxf(d2[4*q+2], d2[4*q+3])));
    }
    const float total = wave_reduce_sum(wsum_local);
    const float bound = M0 * total;

    // Phase 1: value-space bisection. Invariant: cnt(vlo)=wlo < bound <= whi=cnt(vhi).
    float vlo = -1.0f, wlo = 0.0f;
    float vhi = wave_reduce_max(vmax_local), whi = total;
    #pragma unroll 1
    for (int it = 0; it < 48; ++it) {
        if (whi - wlo <= 0.75f) break;               // ~<=2 elements remain
        const float vmid = 0.5f * (vlo + vhi);
        if (!(vmid > vlo && vmid < vhi)) break;      // adjacent floats (ties)
        float c = 0.0f;
        #pragma unroll
        for (int j = 0; j < PER_LANE; ++j)
            c += (d2[j] <= vmid) ? w[j] : 0.0f;
        c = wave_reduce_sum(c);
        if (c >= bound) { vhi = vmid; whi = c; }
        else            { vlo = vmid; wlo = c; }     // wave-uniform branch
    }

    // Phase 2: exact extraction - ascending distinct values above vlo.
    float r2 = vhi, W = wlo;
    #pragma unroll 1
    for (int step = 0; step < 64; ++step) {
        // smallest value > vlo (by invariant it lies in (vlo, vhi])
        float m = __builtin_inff();
        #pragma unroll
        for (int j = 0; j < PER_LANE; ++j)
            m = fminf(m, (d2[j] > vlo) ? d2[j] : __builtin_inff());
        m = wave_reduce_min(m);
        float c = 0.0f;
        #pragma unroll
        for (int j = 0; j < PER_LANE; ++j)
            c += (d2[j] <= m) ? w[j] : 0.0f;
        c = wave_reduce_sum(c);
        if (c >= bound) { r2 = m; W = wlo; break; }  // wlo = cnt(values < m)
        vlo = m; wlo = c;
    }

    // Phase 3: S = sum_{d2 < r2} w*d2  (set membership exact; W already known).
    float S = 0.0f;
    #pragma unroll
    for (int j = 0; j < PER_LANE; ++j)
        if (d2[j] < r2) S = fmaf(w[j], d2[j], S);
    S = wave_reduce_sum(S);

    const float margin = fmaxf(bound - W, 0.0f);     // clamp FP-noise sign flip
    const float val = fmaxf(fmaf(r2, margin, S), 0.0f);
    if (lane == 0) out[gwave] = sqrtf(val / bound);
}

extern "C" void kernel_launch(void* const* d_in, const int* in_sizes, int n_in,
                              void* d_out, int out_size, void* d_ws, size_t ws_size,
                              hipStream_t stream) {
    const float* inputs = (const float*)d_in[0];   // [B, M, 2]
    const float* weight = (const float*)d_in[1];   // [B, M]
    const float* grid   = (const float*)d_in[2];   // [N, 2]
    float* out = (float*)d_out;                    // [B, N] f32

    const int N = in_sizes[2] / 2;                 // 6561
    const int B = out_size / N;                    // 2
    // M hard-wired to 2048 (PER_LANE*64).

    const int total_waves = B * N;                 // 13122
    const int waves_per_block = 256 / 64;
    const int blocks = (total_waves + waves_per_block - 1) / waves_per_block;

    dtm_kernel<<<blocks, 256, 0, stream>>>(inputs, weight, grid, out, B, N);
}